// Round 5
// baseline (37.769 us; speedup 1.0000x reference)
//
#include <hip/hip_runtime.h>

namespace {

constexpr int N  = 50000;
constexpr int R  = 10;
constexpr int DD = 5;
constexpr int RN = R * N;        // 500000
constexpr int DN = DD * N;       // 250000
constexpr int E  = 10000000;
constexpr int EP = E / 2;        // edge pairs

// bitmask geometry
constexpr int ZB_BLOCKS = (DN + 255) / 256;          // 977
constexpr int ZB_WORDS  = ZB_BLOCKS * 256 / 32;      // 7816 u32 (31264 B)

// K1 partition: bits + acc-init only (everything upstream of scatter)
constexpr int AC_BLOCKS  = (RN / 4 + 255) / 256;     // 489
constexpr int PRE_BLOCKS = ZB_BLOCKS + AC_BLOCKS;

// K3 partition: syn + neuron + shift
constexpr int SYN_BLOCKS  = (RN / 4 + 255) / 256;    // 489
constexpr int NEUR_BLOCKS = (N + 255) / 256;         // 196
constexpr int SH_BLOCKS   = ((DN - N) / 4 + 255) / 256; // 196
constexpr int POST_BLOCKS = SYN_BLOCKS + NEUR_BLOCKS + SH_BLOCKS;

constexpr int SC_GRID = 1280;    // 5 blocks/CU (LDS-capped), grid-stride

// ---------------------------------------------------------------------------
// K1: spike bitmask + acc = inputs  (the only work the scatter depends on)
__global__ __launch_bounds__(256) void pre_kernel(
    const float*  __restrict__ z_buf,
    unsigned int* __restrict__ bits,
    const float4* __restrict__ inputs,
    float4*       __restrict__ acc)
{
    int b = blockIdx.x;
    int tid = threadIdx.x;

    if (b < ZB_BLOCKS) {
        int i = b * 256 + tid;
        float zv = (i < DN) ? z_buf[i] : 0.0f;
        unsigned long long m = __ballot(zv != 0.0f);
        if ((tid & 63) == 0) {
            int w = i >> 5;
            bits[w]     = (unsigned int)m;
            bits[w + 1] = (unsigned int)(m >> 32);
        }
    } else {
        int i = (b - ZB_BLOCKS) * 256 + tid;
        if (i < RN / 4) acc[i] = inputs[i];
    }
}

// ---------------------------------------------------------------------------
// K2: sparse scatter  acc[row] += rec_w[e]  iff bit(col).
// Bitmask in LDS; idx as int4 (2 edges/load); unroll x4 for MLP.
__device__ __forceinline__ void edge_pair(
    const int4 a, int p, const unsigned int* bits,
    const float* __restrict__ rec_w, float* __restrict__ acc)
{
    unsigned int w0 = bits[a.y >> 5];
    unsigned int w1 = bits[a.w >> 5];
    if ((w0 >> (a.y & 31)) & 1u) atomicAdd(acc + a.x, rec_w[2 * p]);
    if ((w1 >> (a.w & 31)) & 1u) atomicAdd(acc + a.z, rec_w[2 * p + 1]);
}

__global__ __launch_bounds__(256) void scatter_kernel(
    const float* __restrict__ rec_w,
    const int4*  __restrict__ idx4,          // [p] = (row0, col0, row1, col1)
    const unsigned int* __restrict__ bits_g,
    float*       __restrict__ acc)
{
    __shared__ unsigned int bits[ZB_WORDS];
    for (int i = threadIdx.x; i < ZB_WORDS; i += 256)
        bits[i] = bits_g[i];
    __syncthreads();

    const int gs = SC_GRID * 256;
    int p = blockIdx.x * 256 + threadIdx.x;
    for (; p + 3 * gs < EP; p += 4 * gs) {
        int4 a = idx4[p];
        int4 b = idx4[p + gs];
        int4 c = idx4[p + 2 * gs];
        int4 d = idx4[p + 3 * gs];
        edge_pair(a, p,          bits, rec_w, acc);
        edge_pair(b, p + gs,     bits, rec_w, acc);
        edge_pair(c, p + 2 * gs, bits, rec_w, acc);
        edge_pair(d, p + 3 * gs, bits, rec_w, acc);
    }
    for (; p < EP; p += gs) {
        int4 a = idx4[p];
        edge_pair(a, p, bits, rec_w, acc);
    }
}

// ---------------------------------------------------------------------------
// K3: syn update (needs acc) + neuron update + delay-buffer shift
__global__ __launch_bounds__(256) void post_kernel(
    const float4* __restrict__ acc,
    const float*  __restrict__ psc_rise,
    const float*  __restrict__ psc,
    const float*  __restrict__ syn_decay,
    const float*  __restrict__ psc_initial,
    const float*  __restrict__ z_buf,
    const float*  __restrict__ v,
    const float*  __restrict__ r,
    const float*  __restrict__ asc1,
    const float*  __restrict__ asc2,
    const float*  __restrict__ v_th,
    const float*  __restrict__ e_l,
    const float*  __restrict__ v_reset,
    const float*  __restrict__ g,
    const float*  __restrict__ decay,
    const float*  __restrict__ current_factor,
    const float*  __restrict__ t_ref,
    const float2* __restrict__ k,
    const float2* __restrict__ asc_amps,
    const float*  __restrict__ voltage_scale,
    const float*  __restrict__ voltage_offset,
    float*        __restrict__ out)
{
    int b = blockIdx.x;
    int tid = threadIdx.x;

    if (b < SYN_BLOCKS) {
        int j = b * 256 + tid;
        if (j >= RN / 4) return;
        const float4* pr4 = reinterpret_cast<const float4*>(psc_rise);
        const float4* ps4 = reinterpret_cast<const float4*>(psc);
        const float4* sd4 = reinterpret_cast<const float4*>(syn_decay);
        const float4* pi4 = reinterpret_cast<const float4*>(psc_initial);
        float4* opr4 = reinterpret_cast<float4*>(out + 11 * N);
        float4* ops4 = reinterpret_cast<float4*>(out + 21 * N);
        float4 sd = sd4[j];
        float4 pr = pr4[j];
        float4 pi = pi4[j];
        float4 ac = acc[j];
        float4 ps = ps4[j];
        float4 opr, ops;
        opr.x = sd.x * pr.x + ac.x * pi.x;
        opr.y = sd.y * pr.y + ac.y * pi.y;
        opr.z = sd.z * pr.z + ac.z * pi.z;
        opr.w = sd.w * pr.w + ac.w * pi.w;
        ops.x = ps.x * sd.x + sd.x * pr.x;
        ops.y = ps.y * sd.y + sd.y * pr.y;
        ops.z = ps.z * sd.z + sd.z * pr.z;
        ops.w = ps.w * sd.w + sd.w * pr.w;
        opr4[j] = opr;
        ops4[j] = ops;
        return;
    }
    b -= SYN_BLOCKS;
    if (b < NEUR_BLOCKS) {
        int n = b * 256 + tid;
        if (n >= N) return;

        float prev_z = z_buf[n];

        const float2* p2 = reinterpret_cast<const float2*>(psc + n * R);
        float ic = 0.0f;
#pragma unroll
        for (int t = 0; t < R / 2; ++t) {
            float2 pp = p2[t];
            ic += pp.x + pp.y;
        }

        float new_r = fmaxf(r[n] + prev_z * t_ref[n] - 1.0f, 0.0f);   // DT=1

        float2 kk = k[n];
        float2 aa = asc_amps[n];
        float s0 = 1.0f / (1.0f + expf(-kk.x));
        float s1 = 1.0f / (1.0f + expf(-kk.y));
        float a1_old = asc1[n];
        float a2_old = asc2[n];
        float new_a1 = expf(-s0) * a1_old + prev_z * aa.x;
        float new_a2 = expf(-s1) * a2_old + prev_z * aa.y;

        float el = e_l[n];
        float new_v = decay[n] * v[n]
                    + current_factor[n] * (ic + a1_old + a2_old + g[n] * el);

        float vth = v_th[n];
        float v_sc = (new_v - vth) / (vth - el);
        float nz = (v_sc > 0.0f) ? 1.0f : 0.0f;
        if (new_r > 0.0f) nz = 0.0f;
        if (nz > 0.5f) new_v = v_reset[n];

        out[0 * N + n]  = nz;
        out[1 * N + n]  = new_v * voltage_scale[n] + voltage_offset[n];
        out[2 * N + n]  = nz;
        out[7 * N + n]  = new_v;
        out[8 * N + n]  = new_r;
        out[9 * N + n]  = new_a1;
        out[10 * N + n] = new_a2;
        return;
    }
    b -= NEUR_BLOCKS;
    {
        int i = b * 256 + tid;
        if (i < (DN - N) / 4) {
            const float4* src = reinterpret_cast<const float4*>(z_buf);
            float4* dst = reinterpret_cast<float4*>(out + 3 * N);
            dst[i] = src[i];
        }
    }
}

} // namespace

extern "C" void kernel_launch(void* const* d_in, const int* in_sizes, int n_in,
                              void* d_out, int out_size, void* d_ws, size_t ws_size,
                              hipStream_t stream) {
    const float* inputs         = (const float*)d_in[0];
    const float* z_buf          = (const float*)d_in[1];
    const float* v              = (const float*)d_in[2];
    const float* r              = (const float*)d_in[3];
    const float* asc1           = (const float*)d_in[4];
    const float* asc2           = (const float*)d_in[5];
    const float* psc_rise       = (const float*)d_in[6];
    const float* psc            = (const float*)d_in[7];
    const float* rec_w          = (const float*)d_in[8];
    const int*   rec_idx        = (const int*)d_in[9];
    const float* v_th           = (const float*)d_in[10];
    const float* e_l            = (const float*)d_in[11];
    const float* v_reset        = (const float*)d_in[12];
    const float* g              = (const float*)d_in[13];
    const float* decay          = (const float*)d_in[14];
    const float* current_factor = (const float*)d_in[15];
    const float* t_ref          = (const float*)d_in[16];
    const float* k              = (const float*)d_in[17];
    const float* asc_amps       = (const float*)d_in[18];
    const float* syn_decay      = (const float*)d_in[19];
    const float* psc_initial    = (const float*)d_in[20];
    const float* voltage_scale  = (const float*)d_in[21];
    const float* voltage_offset = (const float*)d_in[22];

    float* out = (float*)d_out;
    float* acc = (float*)d_ws;                         // RN floats = 2 MB
    unsigned int* bits = (unsigned int*)(acc + RN);    // ZB_WORDS u32

    // K1: minimal scatter prerequisites (bits + acc seed)
    pre_kernel<<<PRE_BLOCKS, 256, 0, stream>>>(
        z_buf, bits, (const float4*)inputs, (float4*)acc);

    // K2: sparse recurrent scatter (dominant dispatch)
    scatter_kernel<<<SC_GRID, 256, 0, stream>>>(
        rec_w, (const int4*)rec_idx, bits, acc);

    // K3: everything downstream + remaining elementwise work
    post_kernel<<<POST_BLOCKS, 256, 0, stream>>>(
        (const float4*)acc, psc_rise, psc, syn_decay, psc_initial,
        z_buf, v, r, asc1, asc2, v_th, e_l, v_reset, g, decay,
        current_factor, t_ref, (const float2*)k, (const float2*)asc_amps,
        voltage_scale, voltage_offset, out);
}

// Round 6
// 35.845 us; speedup vs baseline: 1.0537x; 1.0537x over previous
//
#include <hip/hip_runtime.h>

namespace {

constexpr int N  = 50000;
constexpr int R  = 10;
constexpr int DD = 5;
constexpr int RN = R * N;        // 500000
constexpr int DN = DD * N;       // 250000
constexpr int E  = 10000000;
constexpr int EP = E / 2;        // edge pairs

// bitmask geometry
constexpr int ZB_BLOCKS = (DN + 255) / 256;          // 977
constexpr int ZB_WORDS  = ZB_BLOCKS * 256 / 32;      // 7816 u32 (31264 B)

// K1 partition: bits + acc-init only (everything upstream of scatter)
constexpr int AC_BLOCKS  = (RN / 4 + 255) / 256;     // 489
constexpr int PRE_BLOCKS = ZB_BLOCKS + AC_BLOCKS;

// K3 partition: syn + neuron + shift
constexpr int SYN_BLOCKS  = (RN / 4 + 255) / 256;    // 489
constexpr int NEUR_BLOCKS = (N + 255) / 256;         // 196
constexpr int SH_BLOCKS   = ((DN - N) / 4 + 255) / 256; // 196
constexpr int POST_BLOCKS = SYN_BLOCKS + NEUR_BLOCKS + SH_BLOCKS;

// scatter: 512-thread blocks, 4 blocks/CU -> 32 waves/CU (100% occupancy
// ceiling; LDS 4 x 31.7 KB = 127 KB <= 160 KB, VGPR 44 <= 64)
constexpr int SC_BLOCK = 512;
constexpr int SC_GRID  = 1024;

// ---------------------------------------------------------------------------
// K1: spike bitmask + acc = inputs  (the only work the scatter depends on)
__global__ __launch_bounds__(256) void pre_kernel(
    const float*  __restrict__ z_buf,
    unsigned int* __restrict__ bits,
    const float4* __restrict__ inputs,
    float4*       __restrict__ acc)
{
    int b = blockIdx.x;
    int tid = threadIdx.x;

    if (b < ZB_BLOCKS) {
        int i = b * 256 + tid;
        float zv = (i < DN) ? z_buf[i] : 0.0f;
        unsigned long long m = __ballot(zv != 0.0f);
        if ((tid & 63) == 0) {
            int w = i >> 5;
            bits[w]     = (unsigned int)m;
            bits[w + 1] = (unsigned int)(m >> 32);
        }
    } else {
        int i = (b - ZB_BLOCKS) * 256 + tid;
        if (i < RN / 4) acc[i] = inputs[i];
    }
}

// ---------------------------------------------------------------------------
// K2: sparse scatter  acc[row] += rec_w[e]  iff bit(col).
// Bitmask in LDS; idx as int4 (2 edges/load); unroll x2.
__device__ __forceinline__ void edge_pair(
    const int4 a, int p, const unsigned int* bits,
    const float* __restrict__ rec_w, float* __restrict__ acc)
{
    unsigned int w0 = bits[a.y >> 5];
    unsigned int w1 = bits[a.w >> 5];
    if ((w0 >> (a.y & 31)) & 1u) atomicAdd(acc + a.x, rec_w[2 * p]);
    if ((w1 >> (a.w & 31)) & 1u) atomicAdd(acc + a.z, rec_w[2 * p + 1]);
}

__global__ __launch_bounds__(SC_BLOCK) void scatter_kernel(
    const float* __restrict__ rec_w,
    const int4*  __restrict__ idx4,          // [p] = (row0, col0, row1, col1)
    const unsigned int* __restrict__ bits_g,
    float*       __restrict__ acc)
{
    __shared__ unsigned int bits[ZB_WORDS];
    for (int i = threadIdx.x; i < ZB_WORDS; i += SC_BLOCK)
        bits[i] = bits_g[i];
    __syncthreads();

    const int gs = SC_GRID * SC_BLOCK;
    int p = blockIdx.x * SC_BLOCK + threadIdx.x;
    for (; p + gs < EP; p += 2 * gs) {
        int4 a = idx4[p];
        int4 b = idx4[p + gs];
        edge_pair(a, p,      bits, rec_w, acc);
        edge_pair(b, p + gs, bits, rec_w, acc);
    }
    if (p < EP) {
        int4 a = idx4[p];
        edge_pair(a, p, bits, rec_w, acc);
    }
}

// ---------------------------------------------------------------------------
// K3: syn update (needs acc) + neuron update + delay-buffer shift
__global__ __launch_bounds__(256) void post_kernel(
    const float4* __restrict__ acc,
    const float*  __restrict__ psc_rise,
    const float*  __restrict__ psc,
    const float*  __restrict__ syn_decay,
    const float*  __restrict__ psc_initial,
    const float*  __restrict__ z_buf,
    const float*  __restrict__ v,
    const float*  __restrict__ r,
    const float*  __restrict__ asc1,
    const float*  __restrict__ asc2,
    const float*  __restrict__ v_th,
    const float*  __restrict__ e_l,
    const float*  __restrict__ v_reset,
    const float*  __restrict__ g,
    const float*  __restrict__ decay,
    const float*  __restrict__ current_factor,
    const float*  __restrict__ t_ref,
    const float2* __restrict__ k,
    const float2* __restrict__ asc_amps,
    const float*  __restrict__ voltage_scale,
    const float*  __restrict__ voltage_offset,
    float*        __restrict__ out)
{
    int b = blockIdx.x;
    int tid = threadIdx.x;

    if (b < SYN_BLOCKS) {
        int j = b * 256 + tid;
        if (j >= RN / 4) return;
        const float4* pr4 = reinterpret_cast<const float4*>(psc_rise);
        const float4* ps4 = reinterpret_cast<const float4*>(psc);
        const float4* sd4 = reinterpret_cast<const float4*>(syn_decay);
        const float4* pi4 = reinterpret_cast<const float4*>(psc_initial);
        float4* opr4 = reinterpret_cast<float4*>(out + 11 * N);
        float4* ops4 = reinterpret_cast<float4*>(out + 21 * N);
        float4 sd = sd4[j];
        float4 pr = pr4[j];
        float4 pi = pi4[j];
        float4 ac = acc[j];
        float4 ps = ps4[j];
        float4 opr, ops;
        opr.x = sd.x * pr.x + ac.x * pi.x;
        opr.y = sd.y * pr.y + ac.y * pi.y;
        opr.z = sd.z * pr.z + ac.z * pi.z;
        opr.w = sd.w * pr.w + ac.w * pi.w;
        ops.x = ps.x * sd.x + sd.x * pr.x;
        ops.y = ps.y * sd.y + sd.y * pr.y;
        ops.z = ps.z * sd.z + sd.z * pr.z;
        ops.w = ps.w * sd.w + sd.w * pr.w;
        opr4[j] = opr;
        ops4[j] = ops;
        return;
    }
    b -= SYN_BLOCKS;
    if (b < NEUR_BLOCKS) {
        int n = b * 256 + tid;
        if (n >= N) return;

        float prev_z = z_buf[n];

        const float2* p2 = reinterpret_cast<const float2*>(psc + n * R);
        float ic = 0.0f;
#pragma unroll
        for (int t = 0; t < R / 2; ++t) {
            float2 pp = p2[t];
            ic += pp.x + pp.y;
        }

        float new_r = fmaxf(r[n] + prev_z * t_ref[n] - 1.0f, 0.0f);   // DT=1

        float2 kk = k[n];
        float2 aa = asc_amps[n];
        float s0 = 1.0f / (1.0f + expf(-kk.x));
        float s1 = 1.0f / (1.0f + expf(-kk.y));
        float a1_old = asc1[n];
        float a2_old = asc2[n];
        float new_a1 = expf(-s0) * a1_old + prev_z * aa.x;
        float new_a2 = expf(-s1) * a2_old + prev_z * aa.y;

        float el = e_l[n];
        float new_v = decay[n] * v[n]
                    + current_factor[n] * (ic + a1_old + a2_old + g[n] * el);

        float vth = v_th[n];
        float v_sc = (new_v - vth) / (vth - el);
        float nz = (v_sc > 0.0f) ? 1.0f : 0.0f;
        if (new_r > 0.0f) nz = 0.0f;
        if (nz > 0.5f) new_v = v_reset[n];

        out[0 * N + n]  = nz;
        out[1 * N + n]  = new_v * voltage_scale[n] + voltage_offset[n];
        out[2 * N + n]  = nz;
        out[7 * N + n]  = new_v;
        out[8 * N + n]  = new_r;
        out[9 * N + n]  = new_a1;
        out[10 * N + n] = new_a2;
        return;
    }
    b -= NEUR_BLOCKS;
    {
        int i = b * 256 + tid;
        if (i < (DN - N) / 4) {
            const float4* src = reinterpret_cast<const float4*>(z_buf);
            float4* dst = reinterpret_cast<float4*>(out + 3 * N);
            dst[i] = src[i];
        }
    }
}

} // namespace

extern "C" void kernel_launch(void* const* d_in, const int* in_sizes, int n_in,
                              void* d_out, int out_size, void* d_ws, size_t ws_size,
                              hipStream_t stream) {
    const float* inputs         = (const float*)d_in[0];
    const float* z_buf          = (const float*)d_in[1];
    const float* v              = (const float*)d_in[2];
    const float* r              = (const float*)d_in[3];
    const float* asc1           = (const float*)d_in[4];
    const float* asc2           = (const float*)d_in[5];
    const float* psc_rise       = (const float*)d_in[6];
    const float* psc            = (const float*)d_in[7];
    const float* rec_w          = (const float*)d_in[8];
    const int*   rec_idx        = (const int*)d_in[9];
    const float* v_th           = (const float*)d_in[10];
    const float* e_l            = (const float*)d_in[11];
    const float* v_reset        = (const float*)d_in[12];
    const float* g              = (const float*)d_in[13];
    const float* decay          = (const float*)d_in[14];
    const float* current_factor = (const float*)d_in[15];
    const float* t_ref          = (const float*)d_in[16];
    const float* k              = (const float*)d_in[17];
    const float* asc_amps       = (const float*)d_in[18];
    const float* syn_decay      = (const float*)d_in[19];
    const float* psc_initial    = (const float*)d_in[20];
    const float* voltage_scale  = (const float*)d_in[21];
    const float* voltage_offset = (const float*)d_in[22];

    float* out = (float*)d_out;
    float* acc = (float*)d_ws;                         // RN floats = 2 MB
    unsigned int* bits = (unsigned int*)(acc + RN);    // ZB_WORDS u32

    // K1: minimal scatter prerequisites (bits + acc seed)
    pre_kernel<<<PRE_BLOCKS, 256, 0, stream>>>(
        z_buf, bits, (const float4*)inputs, (float4*)acc);

    // K2: sparse recurrent scatter (dominant dispatch)
    scatter_kernel<<<SC_GRID, SC_BLOCK, 0, stream>>>(
        rec_w, (const int4*)rec_idx, bits, acc);

    // K3: everything downstream + remaining elementwise work
    post_kernel<<<POST_BLOCKS, 256, 0, stream>>>(
        (const float4*)acc, psc_rise, psc, syn_decay, psc_initial,
        z_buf, v, r, asc1, asc2, v_th, e_l, v_reset, g, decay,
        current_factor, t_ref, (const float2*)k, (const float2*)asc_amps,
        voltage_scale, voltage_offset, out);
}

// Round 7
// 34.876 us; speedup vs baseline: 1.0830x; 1.0278x over previous
//
#include <hip/hip_runtime.h>

namespace {

constexpr int N  = 50000;
constexpr int R  = 10;
constexpr int DD = 5;
constexpr int RN = R * N;        // 500000
constexpr int DN = DD * N;       // 250000
constexpr int E  = 10000000;
constexpr int EP = E / 2;        // edge pairs (int4 loads)
constexpr int EPH = EP / 2;      // per-stream half

// bitmask geometry
constexpr int ZB_BLOCKS = (DN + 255) / 256;          // 977
constexpr int ZB_WORDS  = ZB_BLOCKS * 256 / 32;      // 7816 u32 (31264 B)

// K1 partition: bits + acc-init + neuron (all upstream/independent work)
constexpr int AC_BLOCKS   = (RN / 4 + 255) / 256;    // 489
constexpr int NEUR_BLOCKS = (N + 255) / 256;         // 196
constexpr int PRE_BLOCKS  = ZB_BLOCKS + AC_BLOCKS + NEUR_BLOCKS;

// scatter: 512-thread blocks, 4 blocks/CU co-resident
constexpr int SC_BLOCK = 512;
constexpr int SC_GRID  = 1024;

// K3: syn only
constexpr int SYN_BLOCKS = (RN / 4 + 255) / 256;     // 489

// ---------------------------------------------------------------------------
// K1: spike bitmask + acc = inputs + neuron update
__global__ __launch_bounds__(256) void pre_kernel(
    const float*  __restrict__ z_buf,
    unsigned int* __restrict__ bits,
    const float4* __restrict__ inputs,
    float4*       __restrict__ acc,
    const float*  __restrict__ v,
    const float*  __restrict__ r,
    const float*  __restrict__ asc1,
    const float*  __restrict__ asc2,
    const float*  __restrict__ psc,
    const float*  __restrict__ v_th,
    const float*  __restrict__ e_l,
    const float*  __restrict__ v_reset,
    const float*  __restrict__ g,
    const float*  __restrict__ decay,
    const float*  __restrict__ current_factor,
    const float*  __restrict__ t_ref,
    const float2* __restrict__ k,
    const float2* __restrict__ asc_amps,
    const float*  __restrict__ voltage_scale,
    const float*  __restrict__ voltage_offset,
    float*        __restrict__ out)
{
    int b = blockIdx.x;
    int tid = threadIdx.x;

    if (b < ZB_BLOCKS) {
        int i = b * 256 + tid;
        float zv = (i < DN) ? z_buf[i] : 0.0f;
        unsigned long long m = __ballot(zv != 0.0f);
        if ((tid & 63) == 0) {
            int w = i >> 5;
            bits[w]     = (unsigned int)m;
            bits[w + 1] = (unsigned int)(m >> 32);
        }
        return;
    }
    b -= ZB_BLOCKS;
    if (b < AC_BLOCKS) {
        int i = b * 256 + tid;
        if (i < RN / 4) acc[i] = inputs[i];
        return;
    }
    b -= AC_BLOCKS;
    {
        int n = b * 256 + tid;
        if (n >= N) return;

        float prev_z = z_buf[n];

        const float2* p2 = reinterpret_cast<const float2*>(psc + n * R);
        float ic = 0.0f;
#pragma unroll
        for (int t = 0; t < R / 2; ++t) {
            float2 pp = p2[t];
            ic += pp.x + pp.y;
        }

        float new_r = fmaxf(r[n] + prev_z * t_ref[n] - 1.0f, 0.0f);   // DT=1

        float2 kk = k[n];
        float2 aa = asc_amps[n];
        float s0 = 1.0f / (1.0f + expf(-kk.x));
        float s1 = 1.0f / (1.0f + expf(-kk.y));
        float a1_old = asc1[n];
        float a2_old = asc2[n];
        float new_a1 = expf(-s0) * a1_old + prev_z * aa.x;
        float new_a2 = expf(-s1) * a2_old + prev_z * aa.y;

        float el = e_l[n];
        float new_v = decay[n] * v[n]
                    + current_factor[n] * (ic + a1_old + a2_old + g[n] * el);

        float vth = v_th[n];
        float v_sc = (new_v - vth) / (vth - el);
        float nz = (v_sc > 0.0f) ? 1.0f : 0.0f;
        if (new_r > 0.0f) nz = 0.0f;
        if (nz > 0.5f) new_v = v_reset[n];

        out[0 * N + n]  = nz;
        out[1 * N + n]  = new_v * voltage_scale[n] + voltage_offset[n];
        out[2 * N + n]  = nz;
        out[7 * N + n]  = new_v;
        out[8 * N + n]  = new_r;
        out[9 * N + n]  = new_a1;
        out[10 * N + n] = new_a2;
    }
}

// ---------------------------------------------------------------------------
// K2: sparse scatter, dual-stream software-pipelined; + shift tail.
__device__ __forceinline__ void edge_pair(
    const int4 a, int p, const unsigned int* bits,
    const float* __restrict__ rec_w, float* __restrict__ acc)
{
    unsigned int w0 = bits[a.y >> 5];
    unsigned int w1 = bits[a.w >> 5];
    if ((w0 >> (a.y & 31)) & 1u) atomicAdd(acc + a.x, rec_w[2 * p]);
    if ((w1 >> (a.w & 31)) & 1u) atomicAdd(acc + a.z, rec_w[2 * p + 1]);
}

__global__ __launch_bounds__(SC_BLOCK) void scatter_kernel(
    const float* __restrict__ rec_w,
    const int4*  __restrict__ idx4,          // [p] = (row0, col0, row1, col1)
    const unsigned int* __restrict__ bits_g,
    float*       __restrict__ acc,
    const float* __restrict__ z_buf,
    float*       __restrict__ out)
{
    __shared__ unsigned int bits[ZB_WORDS];
    {
        const uint4* src = reinterpret_cast<const uint4*>(bits_g);
        uint4* dst = reinterpret_cast<uint4*>(bits);
        for (int i = threadIdx.x; i < ZB_WORDS / 4; i += SC_BLOCK)
            dst[i] = src[i];
    }
    __syncthreads();

    const int gs  = SC_GRID * SC_BLOCK;
    const int gid = blockIdx.x * SC_BLOCK + threadIdx.x;

    // Two independent grid-strided streams (lower/upper halves of the pair
    // range), each with one int4 prefetched ahead -> up to 4 loads in flight
    // per thread, and loads always issue before the branchy atomic tail.
    int pA = gid, pB = gid + EPH;
    bool hA = pA < EPH;
    bool hB = pB < EP;
    int4 a = {0, 0, 0, 0}, b = {0, 0, 0, 0};
    if (hA) a = idx4[pA];
    if (hB) b = idx4[pB];
    while (hA || hB) {
        int nA = pA + gs, nB = pB + gs;
        bool hnA = hA && (nA < EPH);
        bool hnB = hB && (nB < EP);
        int4 na = {0, 0, 0, 0}, nb = {0, 0, 0, 0};
        if (hnA) na = idx4[nA];
        if (hnB) nb = idx4[nB];
        if (hA) edge_pair(a, pA, bits, rec_w, acc);
        if (hB) edge_pair(b, pB, bits, rec_w, acc);
        a = na; pA = nA; hA = hnA;
        b = nb; pB = nB; hB = hnB;
    }

    // tail: delay-buffer shift (independent of acc) fills the drain
    {
        const float4* src = reinterpret_cast<const float4*>(z_buf);
        float4* dst = reinterpret_cast<float4*>(out + 3 * N);
        for (int i = gid; i < (DN - N) / 4; i += gs)
            dst[i] = src[i];
    }
}

// ---------------------------------------------------------------------------
// K3: synapse update (the only work downstream of the scatter)
__global__ __launch_bounds__(256) void syn_kernel(
    const float4* __restrict__ acc,
    const float4* __restrict__ psc_rise,
    const float4* __restrict__ psc,
    const float4* __restrict__ syn_decay,
    const float4* __restrict__ psc_initial,
    float4* __restrict__ out_psc_rise,
    float4* __restrict__ out_psc,
    int n4)
{
    int j = blockIdx.x * 256 + threadIdx.x;
    if (j >= n4) return;
    float4 sd = syn_decay[j];
    float4 pr = psc_rise[j];
    float4 pi = psc_initial[j];
    float4 ac = acc[j];
    float4 ps = psc[j];
    float4 opr, ops;
    opr.x = sd.x * pr.x + ac.x * pi.x;
    opr.y = sd.y * pr.y + ac.y * pi.y;
    opr.z = sd.z * pr.z + ac.z * pi.z;
    opr.w = sd.w * pr.w + ac.w * pi.w;
    ops.x = ps.x * sd.x + sd.x * pr.x;
    ops.y = ps.y * sd.y + sd.y * pr.y;
    ops.z = ps.z * sd.z + sd.z * pr.z;
    ops.w = ps.w * sd.w + sd.w * pr.w;
    out_psc_rise[j] = opr;
    out_psc[j]      = ops;
}

} // namespace

extern "C" void kernel_launch(void* const* d_in, const int* in_sizes, int n_in,
                              void* d_out, int out_size, void* d_ws, size_t ws_size,
                              hipStream_t stream) {
    const float* inputs         = (const float*)d_in[0];
    const float* z_buf          = (const float*)d_in[1];
    const float* v              = (const float*)d_in[2];
    const float* r              = (const float*)d_in[3];
    const float* asc1           = (const float*)d_in[4];
    const float* asc2           = (const float*)d_in[5];
    const float* psc_rise       = (const float*)d_in[6];
    const float* psc            = (const float*)d_in[7];
    const float* rec_w          = (const float*)d_in[8];
    const int*   rec_idx        = (const int*)d_in[9];
    const float* v_th           = (const float*)d_in[10];
    const float* e_l            = (const float*)d_in[11];
    const float* v_reset        = (const float*)d_in[12];
    const float* g              = (const float*)d_in[13];
    const float* decay          = (const float*)d_in[14];
    const float* current_factor = (const float*)d_in[15];
    const float* t_ref          = (const float*)d_in[16];
    const float* k              = (const float*)d_in[17];
    const float* asc_amps       = (const float*)d_in[18];
    const float* syn_decay      = (const float*)d_in[19];
    const float* psc_initial    = (const float*)d_in[20];
    const float* voltage_scale  = (const float*)d_in[21];
    const float* voltage_offset = (const float*)d_in[22];

    float* out = (float*)d_out;
    float* acc = (float*)d_ws;                         // RN floats = 2 MB
    unsigned int* bits = (unsigned int*)(acc + RN);    // ZB_WORDS u32

    // K1: bits + acc seed + neuron (all scatter-independent)
    pre_kernel<<<PRE_BLOCKS, 256, 0, stream>>>(
        z_buf, bits, (const float4*)inputs, (float4*)acc,
        v, r, asc1, asc2, psc, v_th, e_l, v_reset, g, decay,
        current_factor, t_ref, (const float2*)k, (const float2*)asc_amps,
        voltage_scale, voltage_offset, out);

    // K2: sparse recurrent scatter (+ shift tail)
    scatter_kernel<<<SC_GRID, SC_BLOCK, 0, stream>>>(
        rec_w, (const int4*)rec_idx, bits, acc, z_buf, out);

    // K3: synapse update
    syn_kernel<<<SYN_BLOCKS, 256, 0, stream>>>(
        (const float4*)acc, (const float4*)psc_rise, (const float4*)psc,
        (const float4*)syn_decay, (const float4*)psc_initial,
        (float4*)(out + 11 * N), (float4*)(out + 21 * N), RN / 4);
}

// Round 8
// 33.124 us; speedup vs baseline: 1.1402x; 1.0529x over previous
//
#include <hip/hip_runtime.h>

namespace {

constexpr int N  = 50000;
constexpr int R  = 10;
constexpr int DD = 5;
constexpr int RN = R * N;        // 500000
constexpr int DN = DD * N;       // 250000
constexpr int E  = 10000000;
constexpr int EP = E / 2;        // edge pairs (int4 loads)
constexpr int EPH = EP / 2;      // per-stream half

// bitmask geometry
constexpr int ZB_BLOCKS = (DN + 255) / 256;          // 977
constexpr int ZB_WORDS  = ZB_BLOCKS * 256 / 32;      // 7816 u32 (31264 B)

// K1 partition: bits + psc seed (syn algebra) + neuron
constexpr int SEED_BLOCKS = (RN / 4 + 255) / 256;    // 489
constexpr int NEUR_BLOCKS = (N + 255) / 256;         // 196
constexpr int PRE_BLOCKS  = ZB_BLOCKS + SEED_BLOCKS + NEUR_BLOCKS;

// scatter: 512-thread blocks, 4 blocks/CU co-resident
constexpr int SC_BLOCK = 512;
constexpr int SC_GRID  = 1024;

// ---------------------------------------------------------------------------
// K1: spike bitmask + psc_rise/psc outputs (seeded, pre-scatter) + neuron.
//   out_psc_rise = syn_decay*psc_rise + inputs*psc_initial   (scatter adds
//                  rec_w*psc_initial on top atomically)
//   out_psc      = psc*syn_decay + syn_decay*psc_rise        (no i_rec dep)
__global__ __launch_bounds__(256) void pre_kernel(
    const float*  __restrict__ z_buf,
    unsigned int* __restrict__ bits,
    const float4* __restrict__ inputs4,
    const float*  __restrict__ psc_rise,
    const float*  __restrict__ psc,
    const float*  __restrict__ syn_decay,
    const float*  __restrict__ psc_initial,
    const float*  __restrict__ v,
    const float*  __restrict__ r,
    const float*  __restrict__ asc1,
    const float*  __restrict__ asc2,
    const float*  __restrict__ v_th,
    const float*  __restrict__ e_l,
    const float*  __restrict__ v_reset,
    const float*  __restrict__ g,
    const float*  __restrict__ decay,
    const float*  __restrict__ current_factor,
    const float*  __restrict__ t_ref,
    const float2* __restrict__ k,
    const float2* __restrict__ asc_amps,
    const float*  __restrict__ voltage_scale,
    const float*  __restrict__ voltage_offset,
    float*        __restrict__ out)
{
    int b = blockIdx.x;
    int tid = threadIdx.x;

    if (b < ZB_BLOCKS) {
        int i = b * 256 + tid;
        float zv = (i < DN) ? z_buf[i] : 0.0f;
        unsigned long long m = __ballot(zv != 0.0f);
        if ((tid & 63) == 0) {
            int w = i >> 5;
            bits[w]     = (unsigned int)m;
            bits[w + 1] = (unsigned int)(m >> 32);
        }
        return;
    }
    b -= ZB_BLOCKS;
    if (b < SEED_BLOCKS) {
        int j = b * 256 + tid;
        if (j >= RN / 4) return;
        const float4* pr4 = reinterpret_cast<const float4*>(psc_rise);
        const float4* ps4 = reinterpret_cast<const float4*>(psc);
        const float4* sd4 = reinterpret_cast<const float4*>(syn_decay);
        const float4* pi4 = reinterpret_cast<const float4*>(psc_initial);
        float4* opr4 = reinterpret_cast<float4*>(out + 11 * N);
        float4* ops4 = reinterpret_cast<float4*>(out + 21 * N);
        float4 sd = sd4[j];
        float4 pr = pr4[j];
        float4 pi = pi4[j];
        float4 in = inputs4[j];
        float4 ps = ps4[j];
        float4 opr, ops;
        opr.x = sd.x * pr.x + in.x * pi.x;
        opr.y = sd.y * pr.y + in.y * pi.y;
        opr.z = sd.z * pr.z + in.z * pi.z;
        opr.w = sd.w * pr.w + in.w * pi.w;
        ops.x = ps.x * sd.x + sd.x * pr.x;
        ops.y = ps.y * sd.y + sd.y * pr.y;
        ops.z = ps.z * sd.z + sd.z * pr.z;
        ops.w = ps.w * sd.w + sd.w * pr.w;
        opr4[j] = opr;
        ops4[j] = ops;
        return;
    }
    b -= SEED_BLOCKS;
    {
        int n = b * 256 + tid;
        if (n >= N) return;

        float prev_z = z_buf[n];

        const float2* p2 = reinterpret_cast<const float2*>(psc + n * R);
        float ic = 0.0f;
#pragma unroll
        for (int t = 0; t < R / 2; ++t) {
            float2 pp = p2[t];
            ic += pp.x + pp.y;
        }

        float new_r = fmaxf(r[n] + prev_z * t_ref[n] - 1.0f, 0.0f);   // DT=1

        float2 kk = k[n];
        float2 aa = asc_amps[n];
        float s0 = 1.0f / (1.0f + expf(-kk.x));
        float s1 = 1.0f / (1.0f + expf(-kk.y));
        float a1_old = asc1[n];
        float a2_old = asc2[n];
        float new_a1 = expf(-s0) * a1_old + prev_z * aa.x;
        float new_a2 = expf(-s1) * a2_old + prev_z * aa.y;

        float el = e_l[n];
        float new_v = decay[n] * v[n]
                    + current_factor[n] * (ic + a1_old + a2_old + g[n] * el);

        float vth = v_th[n];
        float v_sc = (new_v - vth) / (vth - el);
        float nz = (v_sc > 0.0f) ? 1.0f : 0.0f;
        if (new_r > 0.0f) nz = 0.0f;
        if (nz > 0.5f) new_v = v_reset[n];

        out[0 * N + n]  = nz;
        out[1 * N + n]  = new_v * voltage_scale[n] + voltage_offset[n];
        out[2 * N + n]  = nz;
        out[7 * N + n]  = new_v;
        out[8 * N + n]  = new_r;
        out[9 * N + n]  = new_a1;
        out[10 * N + n] = new_a2;
    }
}

// ---------------------------------------------------------------------------
// K2: sparse scatter directly into out_psc_rise:
//   out_psc_rise[row] += rec_w[e] * psc_initial[row]   iff bit(col)
// Dual-stream software-pipelined (r7 structure); + shift tail.
__device__ __forceinline__ void edge_pair(
    const int4 a, int p, const unsigned int* bits,
    const float* __restrict__ rec_w, const float* __restrict__ pinit,
    float* __restrict__ opr)
{
    unsigned int w0 = bits[a.y >> 5];
    unsigned int w1 = bits[a.w >> 5];
    if ((w0 >> (a.y & 31)) & 1u)
        atomicAdd(opr + a.x, rec_w[2 * p] * pinit[a.x]);
    if ((w1 >> (a.w & 31)) & 1u)
        atomicAdd(opr + a.z, rec_w[2 * p + 1] * pinit[a.z]);
}

__global__ __launch_bounds__(SC_BLOCK) void scatter_kernel(
    const float* __restrict__ rec_w,
    const int4*  __restrict__ idx4,          // [p] = (row0, col0, row1, col1)
    const unsigned int* __restrict__ bits_g,
    const float* __restrict__ pinit,
    const float* __restrict__ z_buf,
    float*       __restrict__ out)
{
    __shared__ unsigned int bits[ZB_WORDS];
    {
        const uint4* src = reinterpret_cast<const uint4*>(bits_g);
        uint4* dst = reinterpret_cast<uint4*>(bits);
        for (int i = threadIdx.x; i < ZB_WORDS / 4; i += SC_BLOCK)
            dst[i] = src[i];
    }
    __syncthreads();

    float* opr = out + 11 * N;

    const int gs  = SC_GRID * SC_BLOCK;
    const int gid = blockIdx.x * SC_BLOCK + threadIdx.x;

    int pA = gid, pB = gid + EPH;
    bool hA = pA < EPH;
    bool hB = pB < EP;
    int4 a = {0, 0, 0, 0}, b = {0, 0, 0, 0};
    if (hA) a = idx4[pA];
    if (hB) b = idx4[pB];
    while (hA || hB) {
        int nA = pA + gs, nB = pB + gs;
        bool hnA = hA && (nA < EPH);
        bool hnB = hB && (nB < EP);
        int4 na = {0, 0, 0, 0}, nb = {0, 0, 0, 0};
        if (hnA) na = idx4[nA];
        if (hnB) nb = idx4[nB];
        if (hA) edge_pair(a, pA, bits, rec_w, pinit, opr);
        if (hB) edge_pair(b, pB, bits, rec_w, pinit, opr);
        a = na; pA = nA; hA = hnA;
        b = nb; pB = nB; hB = hnB;
    }

    // tail: delay-buffer shift (independent of scatter results)
    {
        const float4* src = reinterpret_cast<const float4*>(z_buf);
        float4* dst = reinterpret_cast<float4*>(out + 3 * N);
        for (int i = gid; i < (DN - N) / 4; i += gs)
            dst[i] = src[i];
    }
}

} // namespace

extern "C" void kernel_launch(void* const* d_in, const int* in_sizes, int n_in,
                              void* d_out, int out_size, void* d_ws, size_t ws_size,
                              hipStream_t stream) {
    const float* inputs         = (const float*)d_in[0];
    const float* z_buf          = (const float*)d_in[1];
    const float* v              = (const float*)d_in[2];
    const float* r              = (const float*)d_in[3];
    const float* asc1           = (const float*)d_in[4];
    const float* asc2           = (const float*)d_in[5];
    const float* psc_rise       = (const float*)d_in[6];
    const float* psc            = (const float*)d_in[7];
    const float* rec_w          = (const float*)d_in[8];
    const int*   rec_idx        = (const int*)d_in[9];
    const float* v_th           = (const float*)d_in[10];
    const float* e_l            = (const float*)d_in[11];
    const float* v_reset        = (const float*)d_in[12];
    const float* g              = (const float*)d_in[13];
    const float* decay          = (const float*)d_in[14];
    const float* current_factor = (const float*)d_in[15];
    const float* t_ref          = (const float*)d_in[16];
    const float* k              = (const float*)d_in[17];
    const float* asc_amps       = (const float*)d_in[18];
    const float* syn_decay      = (const float*)d_in[19];
    const float* psc_initial    = (const float*)d_in[20];
    const float* voltage_scale  = (const float*)d_in[21];
    const float* voltage_offset = (const float*)d_in[22];

    float* out = (float*)d_out;
    unsigned int* bits = (unsigned int*)d_ws;          // ZB_WORDS u32

    // K1: bits + seeded psc outputs + neuron (all scatter-independent)
    pre_kernel<<<PRE_BLOCKS, 256, 0, stream>>>(
        z_buf, bits, (const float4*)inputs, psc_rise, psc, syn_decay,
        psc_initial, v, r, asc1, asc2, v_th, e_l, v_reset, g, decay,
        current_factor, t_ref, (const float2*)k, (const float2*)asc_amps,
        voltage_scale, voltage_offset, out);

    // K2: sparse recurrent scatter straight into out_psc_rise (+ shift tail)
    scatter_kernel<<<SC_GRID, SC_BLOCK, 0, stream>>>(
        rec_w, (const int4*)rec_idx, bits, psc_initial, z_buf, out);
}